// Round 14
// baseline (32.341 us; speedup 1.0000x reference)
//
#include <hip/hip_runtime.h>

// PatchStd: out = sqrt( boxconv7(x^2) - boxconv7(x)^2 ), uniform 7x7 weight w.
// x: [16, 1, 1024, 1024] fp32, zero padding 3 on each side.
//
// R14: double aggregate wave concurrency (the one un-moved lever; per-wave
// VALU/depth/store/chain levers all null R7-R13). 2 output cols/thread ->
// 128 cols/wave -> 8192 waves total = 32/CU nominal, ALL co-resident
// (2048 blocks, 8/CU, LDS 16KB/block = 128KB/CU), SH=16 keeps halo at 1.375.
// Stage: ONE global_load_lds size=16 per row per wave into SEGF=256 slot
// (SO = W0-8 multiple of 4 -> clamped lanes fully OOB, no partial corruption;
// slot >= full 64-lane DMA footprint per R9). Consume: 3x ds_read_b128
// superset from f0=(2*lane+5)&~3 + 8-wide parity select (d=1 even/3 odd
// lanes) -> 8-float window; sliding 7-sums for 2 cols; 7-deep ring [7][2] +
// vertical running sums. Counted vmcnt for 1 load/row + 1 store/output:
//   j<=6:3 | 7:4 | 8:5 | 9-18:6 | 19:5 | 20:4 | 21:3. No barriers.

#define IMG_W 1024
#define IMG_H 1024
#define SH    16            // output rows per block strip
#define TPB   256
#define NR    (SH + 6)      // 22 input rows per strip
#define RING  4
#define SEGF  256           // floats per slot = exact 64-lane size16 footprint

typedef float v4f __attribute__((ext_vector_type(4)));
typedef float v2f __attribute__((ext_vector_type(2)));

#define WAITV(N) asm volatile("s_waitcnt vmcnt(" #N ")" ::: "memory")

__global__ __launch_bounds__(TPB) void patchstd_kernel(
    const float* __restrict__ img, const float* __restrict__ wptr,
    float* __restrict__ out)
{
    __shared__ float lds[4 * RING * SEGF];          // 16 KB

    const int tx   = threadIdx.x;
    const int w_   = tx >> 6;                       // wave id 0..3 (uniform)
    const int lane = tx & 63;
    const int y0   = blockIdx.y * SH;
    const float* base  = img + (size_t)blockIdx.z * (IMG_W * IMG_H);
    float*       obase = out + (size_t)blockIdx.z * (IMG_W * IMG_H);
    const float w = wptr[0];

    // Wave covers 128 output cols at W0; thread covers gcol0, gcol0+1.
    const int W0    = 512 * blockIdx.x + 128 * w_;
    const int SO    = W0 - 8;                       // segment origin col (mod 4 == 0)
    const int gcol0 = W0 + 2 * lane;
    // Per-lane DMA source col, clamped in 4-float quads (fully OOB or valid).
    const int colA = min(max(SO + 4 * lane, 0), IMG_W - 4);
    const float* gA = base + colA;
    float* const seg0 = &lds[w_ * (RING * SEGF)];

    // Issue row j's segment DMA into ring slot j&3 (one dwordx4 LDS-DMA).
    auto issue = [&](int j) {
        const int rc = min(max(y0 - 3 + j, 0), IMG_H - 1);    // clamped row
        float* sl = seg0 + (j & (RING - 1)) * SEGF;
        __builtin_amdgcn_global_load_lds(
            (const __attribute__((address_space(1))) void*)(gA + (size_t)rc * IMG_W),
            (__attribute__((address_space(3))) void*)sl, 16, 0, 0);
    };

    float rh[7][2], rq[7][2];                       // h/q ring (7 rows x 2 cols)
    float vh[2] = {0.f, 0.f};                       // vertical running sums
    float vq[2] = {0.f, 0.f};

    // Superset-read geometry (all lane-constant):
    const int f0 = (2 * lane + 5) & ~3;             // aligned quad start
    const bool odd = (lane & 1);                    // select offset 1 or 3
    const float* segq0 = seg0 + f0;

    issue(0); issue(1); issue(2);                   // 3-deep pipeline fill

    #pragma unroll
    for (int j = 0; j < NR; ++j) {
        if (j + 3 < NR) issue(j + 3);

        if      (j <= 6)  WAITV(3);
        else if (j == 7)  WAITV(4);
        else if (j == 8)  WAITV(5);
        else if (j <= 18) WAITV(6);
        else if (j == 19) WAITV(5);
        else if (j == 20) WAITV(4);
        else              WAITV(3);

        // Consume row j: 3x ds_read_b128 superset, parity-select 8-float window.
        const v4f* p = (const v4f*)(segq0 + (j & (RING - 1)) * SEGF);
        v4f A = p[0], B = p[1], C = p[2];
        float raw[12] = {A.x,A.y,A.z,A.w, B.x,B.y,B.z,B.w, C.x,C.y,C.z,C.w};
        float v[8];
        #pragma unroll
        for (int i = 0; i < 8; ++i) v[i] = odd ? raw[3 + i] : raw[1 + i];
        // Edge zero-patch: v[i] covers col gcol0-3+i.
        if (gcol0 == 0)    { v[0]=0.f; v[1]=0.f; v[2]=0.f; }
        if (gcol0 == 2)    { v[0]=0.f; }
        if (gcol0 == 1020) { v[7]=0.f; }
        if (gcol0 == 1022) { v[5]=0.f; v[6]=0.f; v[7]=0.f; }

        float h[2], q[2];
        const int R = y0 - 3 + j;
        if (R < 0 || R >= IMG_H) {                  // block-uniform branch
            h[0]=0.f; h[1]=0.f; q[0]=0.f; q[1]=0.f;
        } else {
            float s = v[0]+v[1]+v[2]+v[3]+v[4]+v[5]+v[6];
            h[0] = s;
            h[1] = s - v[0] + v[7];
            float sq[8];
            #pragma unroll
            for (int i = 0; i < 8; ++i) sq[i] = v[i] * v[i];
            float t = sq[0]+sq[1]+sq[2]+sq[3]+sq[4]+sq[5]+sq[6];
            q[0] = t;
            q[1] = t - sq[0] + sq[7];
        }

        if (j < 6) {                                // warm the vertical window
            #pragma unroll
            for (int k = 0; k < 2; ++k) {
                rh[j][k] = h[k]; rq[j][k] = q[k];
                vh[k] += h[k];   vq[k] += q[k];
            }
            if (j == 5) {
                rh[6][0]=0.f; rh[6][1]=0.f; rq[6][0]=0.f; rq[6][1]=0.f;
            }
        } else {                                    // steady state: emit a row
            const int s = j % 7;                    // departing row's slot
            float o[2];
            #pragma unroll
            for (int k = 0; k < 2; ++k) {
                vh[k] += h[k] - rh[s][k];
                vq[k] += q[k] - rq[s][k];
                rh[s][k] = h[k]; rq[s][k] = q[k];
                float mean = w * vh[k];
                float var  = fmaf(w, vq[k], -(mean * mean));
                o[k] = __builtin_amdgcn_sqrtf(fmaxf(var, 0.f));
            }
            v2f ov; ov.x = o[0]; ov.y = o[1];
            *reinterpret_cast<v2f*>(obase + (size_t)(y0 + j - 6) * IMG_W + gcol0) = ov;
        }
    }
}

extern "C" void kernel_launch(void* const* d_in, const int* in_sizes, int n_in,
                              void* d_out, int out_size, void* d_ws, size_t ws_size,
                              hipStream_t stream) {
    const float* img = (const float*)d_in[0];
    const float* wt  = (const float*)d_in[1];
    float* out = (float*)d_out;
    const int batch = in_sizes[0] / (IMG_W * IMG_H);   // 16
    dim3 grid(IMG_W / 512, IMG_H / SH, batch);         // (2, 64, 16) = 2048 blocks
    patchstd_kernel<<<grid, dim3(TPB, 1, 1), 0, stream>>>(img, wt, out);
}

// Round 15
// 28.060 us; speedup vs baseline: 1.1525x; 1.1525x over previous
//
#include <hip/hip_runtime.h>

// PatchStd: out = sqrt( boxconv7(x^2) - boxconv7(x)^2 ), uniform 7x7 weight w.
// x: [16, 1, 1024, 1024] fp32, zero padding 3 on each side.
//
// R15 = R11's exact structure (the 29.0us best: wave-private LDS row-ring,
// RING=4, global_load_lds DMA 3 rows ahead, counted s_waitcnt vmcnt,
// 4 cols/thread, in-loop stores) with SH=32: the work-amortization lever —
// the ONLY lever that has produced a win since the DMA structure landed
// (R11: SH 8->16 = -4.9us). Input rows per output row 1.375 -> 1.1875;
// warmup/drain generations halve (512 blocks). Concurrency drops to 8
// nominal waves/CU — R14 showed insensitivity at 12-24, this probes below.
// Wait table = R11's validated formula extended to NR=38.
// SEGF=320 = full 64-lane DMA footprint (R9 lesson). No barriers.

#define IMG_W 1024
#define IMG_H 1024
#define SH    32            // output rows per block strip
#define TPB   256
#define NR    (SH + 6)      // 38 input rows per strip
#define RING  4
#define SEGF  320           // floats per LDS slot (272 used; 320 = DMA footprint)

typedef float v4f __attribute__((ext_vector_type(4)));

#define WAITV(N) asm volatile("s_waitcnt vmcnt(" #N ")" ::: "memory")

__global__ __launch_bounds__(TPB) void patchstd_kernel(
    const float* __restrict__ img, const float* __restrict__ wptr,
    float* __restrict__ out)
{
    __shared__ float lds[4 * RING * SEGF];          // 20 KB

    const int tx   = threadIdx.x;
    const int w_   = tx >> 6;                       // wave id 0..3 (uniform)
    const int lane = tx & 63;
    const int c0   = tx << 2;                       // first of 4 output cols
    const int y0   = blockIdx.y * SH;
    const float* base  = img + (size_t)blockIdx.z * (IMG_W * IMG_H);
    float*       obase = out + (size_t)blockIdx.z * (IMG_W * IMG_H);
    const float w = wptr[0];

    // Wave w_ covers output cols [256w, 256w+256); segment = cols Sw..Sw+271
    // (Sw = 256w-8); thread's 12-float window (c0-4..c0+7) is at segment
    // float index 4*lane+4. Per-lane global cols clamped in-row (clamped
    // lanes land in padding or are zero-patched at consume).
    const int Sw   = 256 * w_ - 8;
    const int colA = min(max(Sw + 4 * lane, 0), IMG_W - 4);   // dwordx4 quad
    const int colB = min(max(Sw + 256 + lane, 0), IMG_W - 1); // dword tail
    const float* gA = base + colA;
    const float* gB = base + colB;
    float* const seg0 = &lds[w_ * (RING * SEGF)];

    // Issue row j's segment DMA into ring slot j&3 (wave-uniform LDS base).
    auto issue = [&](int j) {
        const int rc = min(max(y0 - 3 + j, 0), IMG_H - 1);    // clamped row
        const size_t ro = (size_t)rc * IMG_W;
        float* sl = seg0 + (j & (RING - 1)) * SEGF;
        __builtin_amdgcn_global_load_lds(
            (const __attribute__((address_space(1))) void*)(gA + ro),
            (__attribute__((address_space(3))) void*)sl, 16, 0, 0);
        __builtin_amdgcn_global_load_lds(
            (const __attribute__((address_space(1))) void*)(gB + ro),
            (__attribute__((address_space(3))) void*)(sl + 256), 4, 0, 0);
    };

    // Horizontal 7-sums for 4 output cols from 12 raw values
    // (window for col c0+k = v[k+1..k+7]).
    auto hsum = [&](const float* v, float* h, float* q) {
        float s = v[1]+v[2]+v[3]+v[4]+v[5]+v[6]+v[7];
        h[0] = s;
        s = s - v[1] + v[8];  h[1] = s;
        s = s - v[2] + v[9];  h[2] = s;
        h[3] = s - v[3] + v[10];
        float sq[11];
        #pragma unroll
        for (int i = 1; i <= 10; ++i) sq[i] = v[i] * v[i];
        float t = sq[1]+sq[2]+sq[3]+sq[4]+sq[5]+sq[6]+sq[7];
        q[0] = t;
        t = t - sq[1] + sq[8];  q[1] = t;
        t = t - sq[2] + sq[9];  q[2] = t;
        q[3] = t - sq[3] + sq[10];
    };

    float rh[7][4], rq[7][4];                       // h/q ring (7 rows)
    float vh[4] = {0.f,0.f,0.f,0.f};                // vertical running sums
    float vq[4] = {0.f,0.f,0.f,0.f};

    issue(0); issue(1); issue(2);                   // 3-deep pipeline fill

    // Full unroll: ring slots, vmcnt immediates, guards all compile-time.
    // vmcnt(N) at iter j = vm-ops younger than row j's 2 loads, issue order
    // (2 loads/row for rows j+1..min(j+3,37); stores from iters
    // [max(6,j-3), j-1], 1 each). Formula validated by R8/R11 pass:
    //   j<=6:6 | 7:7 | 8:8 | 9..34:9 | 35:7 | 36:5 | 37:3.
    #pragma unroll
    for (int j = 0; j < NR; ++j) {
        if (j + 3 < NR) issue(j + 3);

        if      (j <= 6)  WAITV(6);
        else if (j == 7)  WAITV(7);
        else if (j == 8)  WAITV(8);
        else if (j <= 34) WAITV(9);
        else if (j == 35) WAITV(7);
        else if (j == 36) WAITV(5);
        else              WAITV(3);

        // Consume row j from LDS: 3x ds_read_b128.
        const float* seg = seg0 + (j & (RING - 1)) * SEGF;
        const v4f* p = (const v4f*)(seg + 4 * lane + 4);
        v4f A = p[0], B = p[1], C = p[2];
        float v[12] = {A.x,A.y,A.z,A.w, B.x,B.y,B.z,B.w, C.x,C.y,C.z,C.w};
        if (tx == 0)   { v[0]=0.f; v[1]=0.f; v[2]=0.f;  v[3]=0.f;  }
        if (tx == 255) { v[8]=0.f; v[9]=0.f; v[10]=0.f; v[11]=0.f; }

        float h[4], q[4];
        const int R = y0 - 3 + j;
        if (R < 0 || R >= IMG_H) {                  // block-uniform branch
            #pragma unroll
            for (int k = 0; k < 4; ++k) { h[k] = 0.f; q[k] = 0.f; }
        } else {
            hsum(v, h, q);
        }

        if (j < 6) {                                // warm the vertical window
            #pragma unroll
            for (int k = 0; k < 4; ++k) {
                rh[j][k] = h[k]; rq[j][k] = q[k];
                vh[k] += h[k];   vq[k] += q[k];
            }
            if (j == 5) {
                #pragma unroll
                for (int k = 0; k < 4; ++k) { rh[6][k] = 0.f; rq[6][k] = 0.f; }
            }
        } else {                                    // steady state: emit a row
            const int s = j % 7;                    // departing row's slot
            float o[4];
            #pragma unroll
            for (int k = 0; k < 4; ++k) {
                vh[k] += h[k] - rh[s][k];
                vq[k] += q[k] - rq[s][k];
                rh[s][k] = h[k]; rq[s][k] = q[k];
                float mean = w * vh[k];
                float var  = fmaf(w, vq[k], -(mean * mean));
                o[k] = __builtin_amdgcn_sqrtf(fmaxf(var, 0.f));
            }
            *reinterpret_cast<float4*>(obase + (size_t)(y0 + j - 6) * IMG_W + c0) =
                make_float4(o[0], o[1], o[2], o[3]);
        }
    }
}

extern "C" void kernel_launch(void* const* d_in, const int* in_sizes, int n_in,
                              void* d_out, int out_size, void* d_ws, size_t ws_size,
                              hipStream_t stream) {
    const float* img = (const float*)d_in[0];
    const float* wt  = (const float*)d_in[1];
    float* out = (float*)d_out;
    const int batch = in_sizes[0] / (IMG_W * IMG_H);   // 16
    dim3 grid(1, IMG_H / SH, batch);                   // 512 blocks
    patchstd_kernel<<<grid, dim3(TPB, 1, 1), 0, stream>>>(img, wt, out);
}